// Round 2
// baseline (1567.982 us; speedup 1.0000x reference)
//
#include <hip/hip_runtime.h>

#define BB 32
#define NN 512
#define HH 512
#define KT (NN * HH)  // 262144
constexpr float QK_SCALE = 0.04419417382415922f; // 1/sqrt(512)

using bf16x8 = __attribute__((ext_vector_type(8))) short;
using f32x4  = __attribute__((ext_vector_type(4))) float;

// fp32 -> bf16 round-to-nearest-even (inputs finite; no NaN path needed)
__device__ __forceinline__ short f2bf(float f) {
  unsigned int u = __float_as_uint(f);
  unsigned int r = (u + 0x7FFFu + ((u >> 16) & 1u)) >> 16;
  return (short)r;
}

// async global->LDS, 16B per lane, LDS dest = wave-uniform base + lane*16
#define GLOAD_LDS16(g, l)                                              \
  __builtin_amdgcn_global_load_lds(                                    \
      (const __attribute__((address_space(1))) void*)(g),              \
      (__attribute__((address_space(3))) void*)(l), 16, 0, 0)

// ---------------------------------------------------------------------------
// prep_x: x fp32 [B][N][H] -> xbf bf16 (same layout) and xT bf16 [B][H][N]
// ---------------------------------------------------------------------------
__global__ __launch_bounds__(256) void prep_x(const float* __restrict__ x,
                                              short* __restrict__ xbf,
                                              short* __restrict__ xT) {
  __shared__ float tile[32][33];
  const int b = blockIdx.z;
  const int n0 = blockIdx.y * 32, h0 = blockIdx.x * 32;
  const int t = threadIdx.x;
  const int i = t >> 3;
  const int j4 = (t & 7) * 4;
  const float4 v = *(const float4*)&x[((long)b * NN + n0 + i) * HH + h0 + j4];
  short o[4] = {f2bf(v.x), f2bf(v.y), f2bf(v.z), f2bf(v.w)};
  *(uint2*)&xbf[((long)b * NN + n0 + i) * HH + h0 + j4] = *(uint2*)o;
  tile[i][j4 + 0] = v.x; tile[i][j4 + 1] = v.y;
  tile[i][j4 + 2] = v.z; tile[i][j4 + 3] = v.w;
  __syncthreads();
  short p[4] = {f2bf(tile[j4 + 0][i]), f2bf(tile[j4 + 1][i]),
                f2bf(tile[j4 + 2][i]), f2bf(tile[j4 + 3][i])};
  *(uint2*)&xT[((long)b * HH + h0 + i) * NN + n0 + j4] = *(uint2*)p;
}

// ---------------------------------------------------------------------------
// prep_w: Wq/Wk fp32 [H][D] -> Wqt/Wkt bf16 [D][H]
// ---------------------------------------------------------------------------
__global__ __launch_bounds__(256) void prep_w(const float* __restrict__ Wq,
                                              const float* __restrict__ Wk,
                                              short* __restrict__ Wqt,
                                              short* __restrict__ Wkt) {
  __shared__ float tile[32][33];
  const float* W = blockIdx.z ? Wk : Wq;
  short* Wt = blockIdx.z ? Wkt : Wqt;
  const int h0 = blockIdx.y * 32, d0 = blockIdx.x * 32;
  const int t = threadIdx.x;
  const int i = t >> 3;
  const int j4 = (t & 7) * 4;
  const float4 v = *(const float4*)&W[(long)(h0 + i) * HH + d0 + j4];
  tile[i][j4 + 0] = v.x; tile[i][j4 + 1] = v.y;
  tile[i][j4 + 2] = v.z; tile[i][j4 + 3] = v.w;
  __syncthreads();
  short p[4] = {f2bf(tile[j4 + 0][i]), f2bf(tile[j4 + 1][i]),
                f2bf(tile[j4 + 2][i]), f2bf(tile[j4 + 3][i])};
  *(uint2*)&Wt[(long)(d0 + i) * HH + h0 + j4] = *(uint2*)p;
}

// ---------------------------------------------------------------------------
// gemm128: C = A[M][K] x Bt[N][K]^T, bf16 in / fp32 acc. m97 structure:
// 128x128 tile, BK=64, 4 waves (2x2), global_load_lds width=16 staging into
// contiguous unpadded LDS (layout must match lane order — no padding).
// z-dim: A += z*sA, Bt += z*sB, C += z*sC, bias = (z&1)? bias1 : bias0.
// ---------------------------------------------------------------------------
template <int WRITE_BF16>
__global__ __launch_bounds__(256) void gemm128(const short* __restrict__ A,
                                               const short* __restrict__ Bt,
                                               void* __restrict__ Cv,
                                               const float* __restrict__ bias0,
                                               const float* __restrict__ bias1,
                                               float scale, int Nc, int K,
                                               long sA, long sB, long sC) {
  __shared__ short As[128 * 64];  // row-major, row stride 64 bf16 = 128 B
  __shared__ short Bs[128 * 64];
  const int z = blockIdx.z;
  A += (long)z * sA;
  Bt += (long)z * sB;
  const float* bias = (z & 1) ? bias1 : bias0;
  const int m0 = blockIdx.x * 128, n0 = blockIdx.y * 128;
  const int t = threadIdx.x, wave = t >> 6, lane = t & 63;
  const int lrow = lane & 15, lq = lane >> 4;
  const int wm = wave & 1, wn = wave >> 1;
  const int sgrow = lane >> 3;       // row within 8-row segment
  const int sgcol = (lane & 7) * 8;  // k-element offset (16 B granule)
  f32x4 acc[4][4] = {};
  for (int k0 = 0; k0 < K; k0 += 64) {
#pragma unroll
    for (int r = 0; r < 4; ++r) {
      const int s = wave * 4 + r;  // segment 0..15 = 8 rows of the tile
      const short* ga = A + (long)(m0 + s * 8 + sgrow) * K + k0 + sgcol;
      const short* gb = Bt + (long)(n0 + s * 8 + sgrow) * K + k0 + sgcol;
      GLOAD_LDS16(ga, As + s * 512);
      GLOAD_LDS16(gb, Bs + s * 512);
    }
    __syncthreads();
#pragma unroll
    for (int kk = 0; kk < 64; kk += 32) {
      bf16x8 af[4], bf[4];
#pragma unroll
      for (int mt = 0; mt < 4; ++mt)
        af[mt] = *(const bf16x8*)&As[(wm * 64 + mt * 16 + lrow) * 64 + kk + lq * 8];
#pragma unroll
      for (int nt = 0; nt < 4; ++nt)
        bf[nt] = *(const bf16x8*)&Bs[(wn * 64 + nt * 16 + lrow) * 64 + kk + lq * 8];
#pragma unroll
      for (int mt = 0; mt < 4; ++mt)
#pragma unroll
        for (int nt = 0; nt < 4; ++nt)
          acc[mt][nt] = __builtin_amdgcn_mfma_f32_16x16x32_bf16(
              af[mt], bf[nt], acc[mt][nt], 0, 0, 0);
    }
    __syncthreads();
  }
  const long cb = (long)z * sC;
#pragma unroll
  for (int mt = 0; mt < 4; ++mt)
#pragma unroll
    for (int nt = 0; nt < 4; ++nt)
#pragma unroll
      for (int r = 0; r < 4; ++r) {
        const int row = m0 + wm * 64 + mt * 16 + lq * 4 + r;  // C/D row=quad*4+reg
        const int col = n0 + wn * 64 + nt * 16 + lrow;        // C/D col=lane&15
        float v = acc[mt][nt][r] * scale;
        if (bias) v += bias[col];
        if (WRITE_BF16)
          ((short*)Cv)[cb + (long)row * Nc + col] = f2bf(v);
        else
          ((float*)Cv)[cb + (long)row * Nc + col] = v;
      }
}

// ---------------------------------------------------------------------------
// sigsoftmax: attention = softmax(sigmoid(scores)) in-place fp32 + bf16 copy.
// sigmoid in (0,1) => stable softmax without max-subtraction.
// ---------------------------------------------------------------------------
__global__ __launch_bounds__(256) void sigsoftmax(float* __restrict__ att,
                                                  short* __restrict__ attbf) {
  const long row = blockIdx.x;
  float* p = att + row * NN;
  const int t = threadIdx.x;
  float2 v = *(float2*)&p[t * 2];
  const float s0 = 1.f / (1.f + __expf(-v.x));
  const float s1 = 1.f / (1.f + __expf(-v.y));
  const float e0 = __expf(s0), e1 = __expf(s1);
  float sum = e0 + e1;
#pragma unroll
  for (int o = 32; o > 0; o >>= 1) sum += __shfl_down(sum, o);
  __shared__ float wsum[4];
  if ((t & 63) == 0) wsum[t >> 6] = sum;
  __syncthreads();
  const float r = 1.f / (wsum[0] + wsum[1] + wsum[2] + wsum[3]);
  const float a0 = e0 * r, a1 = e1 * r;
  float2 o2; o2.x = a0; o2.y = a1;
  *(float2*)&p[t * 2] = o2;
  short pk[2] = {f2bf(a0), f2bf(a1)};
  *(unsigned int*)&attbf[row * NN + t * 2] = *(unsigned int*)pk;
}

// ---------------------------------------------------------------------------
// final_partial: split-K fp32 vector GEMM for out = out1[32][262144] @ Wm.
// HBM-bound on the 512 MB Wm stream (AI = 16 FLOP/B < fp32 VALU roofline).
// Thread owns column j, 32 accumulators (one per batch). out1 values are
// wave-uniform -> scalar s_load broadcasts. partials[s][b][j], S = gridDim.x.
// ---------------------------------------------------------------------------
__global__ __launch_bounds__(256) void final_partial(const float* __restrict__ out1,
                                                     const float* __restrict__ Wm,
                                                     float* __restrict__ part) {
  const int j = blockIdx.y * 256 + threadIdx.x;
  const long kc = KT / gridDim.x;
  const long k0 = (long)blockIdx.x * kc;
  float acc[BB] = {};
  for (long k = k0; k < k0 + kc; k += 8) {
    float w[8];
#pragma unroll
    for (int kk = 0; kk < 8; ++kk) w[kk] = Wm[(k + kk) * HH + j];
#pragma unroll
    for (int b = 0; b < BB; ++b) {
#pragma unroll
      for (int kk = 0; kk < 8; ++kk)
        acc[b] = fmaf(out1[(long)b * KT + k + kk], w[kk], acc[b]);
    }
  }
  float* p = part + (long)blockIdx.x * (BB * HH);
#pragma unroll
  for (int b = 0; b < BB; ++b) p[(long)b * HH + j] = acc[b];
}

// final_reduce: out[b][j] = bm[j] + sum_s part[s][b][j].  256 blocks,
// block owns 64 outputs, 4 s-slices per block reduced via LDS.
__global__ __launch_bounds__(256) void final_reduce(const float* __restrict__ part,
                                                    const float* __restrict__ bm,
                                                    float* __restrict__ out, int S) {
  __shared__ float red[4][64];
  const int fi = blockIdx.x * 64 + (threadIdx.x & 63);
  const int sg = threadIdx.x >> 6;
  float s = 0.f;
  for (int i = sg; i < S; i += 4) s += part[(long)i * (BB * HH) + fi];
  red[sg][threadIdx.x & 63] = s;
  __syncthreads();
  if (sg == 0)
    out[fi] = bm[fi & (HH - 1)] + red[0][threadIdx.x] + red[1][threadIdx.x] +
              red[2][threadIdx.x] + red[3][threadIdx.x];
}

extern "C" void kernel_launch(void* const* d_in, const int* in_sizes, int n_in,
                              void* d_out, int out_size, void* d_ws, size_t ws_size,
                              hipStream_t stream) {
  const float* x  = (const float*)d_in[0];
  const float* Wq = (const float*)d_in[1];
  const float* bq = (const float*)d_in[2];
  const float* Wk = (const float*)d_in[3];
  const float* bk = (const float*)d_in[4];
  const float* Wm = (const float*)d_in[5];
  const float* bm = (const float*)d_in[6];
  float* out = (float*)d_out;                // [32*512]
  float* att = out + (long)BB * HH;          // [32*512*512] fp32 (output 1)

  char* ws = (char*)d_ws;
  const long SZ = (long)BB * NN * HH * 2;    // 16 MiB bf16 buffer
  short* xbf   = (short*)ws;                 // x bf16 [B][N][H]
  short* xT    = (short*)(ws + SZ);          // x^T bf16 [B][H][N]
  short* qb    = (short*)(ws + 2 * SZ);      // q bf16, later attn bf16
  short* kb    = (short*)(ws + 3 * SZ);      // k bf16
  short* wqt   = (short*)(ws + 4 * SZ);      // Wq^T bf16 [D][H]
  short* wkt   = wqt + (long)HH * HH;        // Wk^T bf16 (contiguous: stride HH*HH)
  float* out1f = (float*)(ws + 4 * SZ + 4 * (long)HH * HH);       // [B][N][H] fp32
  float* part  = out1f + (long)BB * KT;      // [512][32][512] fp32 partials

  prep_x<<<dim3(HH / 32, NN / 32, BB), 256, 0, stream>>>(x, xbf, xT);
  prep_w<<<dim3(HH / 32, HH / 32, 2), 256, 0, stream>>>(Wq, Wk, wqt, wkt);

  // q = x@Wq + bq ; k = x@Wk + bk — fused via z in {0,1}
  gemm128<1><<<dim3(BB * NN / 128, HH / 128, 2), 256, 0, stream>>>(
      xbf, wqt, qb, bq, bk, 1.f, HH, HH, 0, (long)HH * HH, (long)BB * NN * HH);

  // scores[b] = q[b] @ k[b]^T * 1/sqrt(d) -> fp32 attention region
  gemm128<0><<<dim3(NN / 128, NN / 128, BB), 256, 0, stream>>>(
      qb, kb, att, nullptr, nullptr, QK_SCALE, NN, HH,
      (long)NN * HH, (long)NN * HH, (long)NN * NN);

  // attention = softmax(sigmoid(scores)); bf16 copy into qb (q dead now)
  sigsoftmax<<<dim3(BB * NN), 256, 0, stream>>>(att, qb);

  // out1[b] = attn[b] @ x[b]  (Bt = xT[b]) -> fp32
  gemm128<0><<<dim3(NN / 128, HH / 128, BB), 256, 0, stream>>>(
      qb, xT, out1f, nullptr, nullptr, 1.f, HH, NN,
      (long)NN * NN, (long)HH * NN, (long)NN * HH);

  // out = out1_flat @ Wm + bm — fp32 vector split-K + deterministic reduce
  final_partial<<<dim3(512, 2), 256, 0, stream>>>(out1f, Wm, part);
  final_reduce<<<dim3(BB * HH / 64), 256, 0, stream>>>(part, bm, out, 512);
}